// Round 3
// baseline (274.890 us; speedup 1.0000x reference)
//
#include <hip/hip_runtime.h>

#define THRESH 0.7f

typedef float v4f __attribute__((ext_vector_type(4)));

// 4 boxes per thread: maximize outstanding 16B loads per wave (latency-bound fix).
__global__ __launch_bounds__(256) void rnet_post_kernel(
    const v4f* __restrict__ cls4,   // [M/2] packed: (bg0,fc0,bg1,fc1)
    const v4f* __restrict__ reg,    // [M] dx1,dy1,dx2,dy2
    const v4f* __restrict__ rects,  // [M] x1,y1,x2,y2
    const int* __restrict__ hptr,
    const int* __restrict__ wptr,
    v4f* __restrict__ out_rects,    // [M]
    v4f* __restrict__ out_scores4,  // [M/4]
    v4f* __restrict__ out_keep4,    // [M/4]
    int M4)                         // M/4
{
    int t = blockIdx.x * blockDim.x + threadIdx.x;
    if (t >= M4) return;

    const float fh = (float)*hptr;
    const float fw = (float)*wptr;

    // Issue all loads up front for ILP.
    v4f c01 = cls4[2 * t];
    v4f c23 = cls4[2 * t + 1];
    v4f rr[4], dd[4];
#pragma unroll
    for (int j = 0; j < 4; ++j) rr[j] = rects[4 * t + j];
#pragma unroll
    for (int j = 0; j < 4; ++j) dd[j] = reg[4 * t + j];

    float sc[4] = {c01.y, c01.w, c23.y, c23.w};

    v4f kp, so;

#pragma unroll
    for (int j = 0; j < 4; ++j) {
        float keep = (sc[j] > THRESH) ? 1.0f : 0.0f;
        v4f r = rr[j];
        v4f d = dd[j];
        float w = r.z - r.x;
        float h = r.w - r.y;
        v4f o;
        o.x = fminf(fmaxf(fmaf(d.x, w, r.x), 0.0f), fw) * keep;
        o.y = fminf(fmaxf(fmaf(d.y, h, r.y), 0.0f), fh) * keep;
        o.z = fminf(fmaxf(fmaf(d.z, w, r.z), 0.0f), fw) * keep;
        o.w = fminf(fmaxf(fmaf(d.w, h, r.w), 0.0f), fh) * keep;
        __builtin_nontemporal_store(o, &out_rects[4 * t + j]);
        kp[j] = keep;
        so[j] = sc[j] * keep;
    }
    __builtin_nontemporal_store(so, &out_scores4[t]);
    __builtin_nontemporal_store(kp, &out_keep4[t]);
}

extern "C" void kernel_launch(void* const* d_in, const int* in_sizes, int n_in,
                              void* d_out, int out_size, void* d_ws, size_t ws_size,
                              hipStream_t stream) {
    const v4f* cls4  = (const v4f*)d_in[0];  // classifier [B,N,2]
    const v4f* reg   = (const v4f*)d_in[1];  // bbox_regress [B,N,4]
    const v4f* rects = (const v4f*)d_in[2];  // input_rects [B,N,4]
    const int* hptr  = (const int*)d_in[3];
    const int* wptr  = (const int*)d_in[4];

    const int M = in_sizes[0] / 2;  // B*N (4,194,304 — divisible by 4)
    const int M4 = M / 4;

    float* out = (float*)d_out;
    v4f* out_rects   = (v4f*)out;             // 4*M floats
    v4f* out_scores4 = (v4f*)(out + 4ll * M); // M floats
    v4f* out_keep4   = (v4f*)(out + 5ll * M); // M floats

    const int block = 256;
    const int grid = (M4 + block - 1) / block;
    rnet_post_kernel<<<grid, block, 0, stream>>>(cls4, reg, rects, hptr, wptr,
                                                 out_rects, out_scores4, out_keep4, M4);
}

// Round 4
// 235.028 us; speedup vs baseline: 1.1696x; 1.1696x over previous
//
#include <hip/hip_runtime.h>

#define THRESH 0.7f

typedef float v4f __attribute__((ext_vector_type(4)));
typedef float v2f __attribute__((ext_vector_type(2)));

// 4 boxes per thread at stride T: ILP (10 independent loads in flight) while
// every load/store instruction stays perfectly lane-coalesced.
__global__ __launch_bounds__(256) void rnet_post_kernel(
    const v2f* __restrict__ cls2,   // [M] pairs: (bg, face)
    const v4f* __restrict__ reg,    // [M]
    const v4f* __restrict__ rects,  // [M]
    const int* __restrict__ hptr,
    const int* __restrict__ wptr,
    v4f*   __restrict__ out_rects,  // [M]
    float* __restrict__ out_scores, // [M]
    float* __restrict__ out_keep,   // [M]
    int T)                          // M/4 threads total
{
    int t = blockIdx.x * blockDim.x + threadIdx.x;
    if (t >= T) return;

    const float fh = (float)*hptr;
    const float fw = (float)*wptr;

    int idx[4] = {t, t + T, t + 2 * T, t + 3 * T};

    // Issue all loads up front — 12 independent vector loads in flight.
    v2f c[4];
    v4f rr[4], dd[4];
#pragma unroll
    for (int j = 0; j < 4; ++j) c[j] = cls2[idx[j]];
#pragma unroll
    for (int j = 0; j < 4; ++j) rr[j] = rects[idx[j]];
#pragma unroll
    for (int j = 0; j < 4; ++j) dd[j] = reg[idx[j]];

#pragma unroll
    for (int j = 0; j < 4; ++j) {
        float score = c[j].y;
        float keep = (score > THRESH) ? 1.0f : 0.0f;
        v4f r = rr[j];
        v4f d = dd[j];
        float w = r.z - r.x;
        float h = r.w - r.y;
        v4f o;
        o.x = fminf(fmaxf(fmaf(d.x, w, r.x), 0.0f), fw) * keep;
        o.y = fminf(fmaxf(fmaf(d.y, h, r.y), 0.0f), fh) * keep;
        o.z = fminf(fmaxf(fmaf(d.z, w, r.z), 0.0f), fw) * keep;
        o.w = fminf(fmaxf(fmaf(d.w, h, r.w), 0.0f), fh) * keep;
        out_rects[idx[j]]  = o;
        out_scores[idx[j]] = score * keep;
        out_keep[idx[j]]   = keep;
    }
}

extern "C" void kernel_launch(void* const* d_in, const int* in_sizes, int n_in,
                              void* d_out, int out_size, void* d_ws, size_t ws_size,
                              hipStream_t stream) {
    const v2f* cls2  = (const v2f*)d_in[0];  // classifier [B,N,2]
    const v4f* reg   = (const v4f*)d_in[1];  // bbox_regress [B,N,4]
    const v4f* rects = (const v4f*)d_in[2];  // input_rects [B,N,4]
    const int* hptr  = (const int*)d_in[3];
    const int* wptr  = (const int*)d_in[4];

    const int M = in_sizes[0] / 2;  // B*N (4,194,304 — divisible by 4)
    const int T = M / 4;

    float* out = (float*)d_out;
    v4f*   out_rects  = (v4f*)out;        // 4*M floats
    float* out_scores = out + 4ll * M;    // M floats
    float* out_keep   = out + 5ll * M;    // M floats

    const int block = 256;
    const int grid = (T + block - 1) / block;
    rnet_post_kernel<<<grid, block, 0, stream>>>(cls2, reg, rects, hptr, wptr,
                                                 out_rects, out_scores, out_keep, T);
}

// Round 5
// 230.909 us; speedup vs baseline: 1.1905x; 1.0178x over previous
//
#include <hip/hip_runtime.h>

#define THRESH 0.7f

typedef float v4f __attribute__((ext_vector_type(4)));
typedef float v2f __attribute__((ext_vector_type(2)));

// Phase A: scores + keep from classifier. 2 boxes/thread, all accesses
// lane-contiguous (1x v4f load, 2x v2f store). 3 streams, 67 MB.
__global__ __launch_bounds__(256) void rnet_post_scores(
    const v4f* __restrict__ cls4,   // [M/2]: (bg0,fc0,bg1,fc1)
    v2f* __restrict__ out_scores2,  // [M/2]
    v2f* __restrict__ out_keep2,    // [M/2]
    int T)                          // M/2
{
    int t = blockIdx.x * blockDim.x + threadIdx.x;
    if (t >= T) return;
    v4f c = cls4[t];
    float k0 = (c.y > THRESH) ? 1.0f : 0.0f;
    float k1 = (c.w > THRESH) ? 1.0f : 0.0f;
    v2f s, k;
    s.x = c.y * k0; s.y = c.w * k1;
    k.x = k0;       k.y = k1;
    out_scores2[t] = s;
    out_keep2[t]   = k;
}

// Phase B: regressed+clipped rects. 1 box/thread, reads keep written by
// phase A (L3-hot). 4 streams, ~218 MB, read-heavy.
__global__ __launch_bounds__(256) void rnet_post_rects(
    const v4f*   __restrict__ reg,      // [M]
    const v4f*   __restrict__ rects,    // [M]
    const float* __restrict__ keep_in,  // [M] (out_keep region)
    const int*   __restrict__ hptr,
    const int*   __restrict__ wptr,
    v4f* __restrict__ out_rects,        // [M]
    int M)
{
    int i = blockIdx.x * blockDim.x + threadIdx.x;
    if (i >= M) return;

    const float fh = (float)*hptr;
    const float fw = (float)*wptr;

    float kp = keep_in[i];
    v4f r = rects[i];
    v4f d = reg[i];
    float w = r.z - r.x;
    float h = r.w - r.y;
    v4f o;
    o.x = fminf(fmaxf(fmaf(d.x, w, r.x), 0.0f), fw) * kp;
    o.y = fminf(fmaxf(fmaf(d.y, h, r.y), 0.0f), fh) * kp;
    o.z = fminf(fmaxf(fmaf(d.z, w, r.z), 0.0f), fw) * kp;
    o.w = fminf(fmaxf(fmaf(d.w, h, r.w), 0.0f), fh) * kp;
    out_rects[i] = o;
}

extern "C" void kernel_launch(void* const* d_in, const int* in_sizes, int n_in,
                              void* d_out, int out_size, void* d_ws, size_t ws_size,
                              hipStream_t stream) {
    const v4f* cls4  = (const v4f*)d_in[0];  // classifier [B,N,2]
    const v4f* reg   = (const v4f*)d_in[1];  // bbox_regress [B,N,4]
    const v4f* rects = (const v4f*)d_in[2];  // input_rects [B,N,4]
    const int* hptr  = (const int*)d_in[3];
    const int* wptr  = (const int*)d_in[4];

    const int M = in_sizes[0] / 2;  // B*N = 4,194,304

    float* out = (float*)d_out;
    v4f*   out_rects   = (v4f*)out;                 // 4*M floats
    v2f*   out_scores2 = (v2f*)(out + 4ll * M);     // M floats
    v2f*   out_keep2   = (v2f*)(out + 5ll * M);     // M floats
    float* keep_f      = out + 5ll * M;

    const int block = 256;
    const int T = M / 2;
    rnet_post_scores<<<(T + block - 1) / block, block, 0, stream>>>(
        cls4, out_scores2, out_keep2, T);
    rnet_post_rects<<<(M + block - 1) / block, block, 0, stream>>>(
        reg, rects, keep_f, hptr, wptr, out_rects, M);
}